// Round 9
// baseline (362.050 us; speedup 1.0000x reference)
//
#include <hip/hip_runtime.h>

#define NN 100000
#define EE 6400000
#define PP 12
#define FF 32

// one-level bucketing: bucket = 128 consecutive node ids
#define VV    128           // nodes per bucket
#define BB    782           // ceil(NN/VV)
#define K1B   800           // sort chunks (blocks)
#define CHK   8000          // edges per chunk (K1B*CHK == EE)
#define NBIN  784           // hist bins padded (782 used)
#define XST   16            // xds row stride (floats): 64B -> one cache line per node
#define K1SEG 400           // chunks per consumer segment (2 segments)
#define CAP2  4576          // per-(bucket,segment) capacity: mean 4096 + 7.5 sigma
#define NR2   9             // max records per thread (ceil(CAP2/512))
#define FPSI  (1.0f / 4294967296.0f)

// ---------------- precompute: probs + collapsed GRU tables ----------------
// tabs layout: [0..11] probs, [16..47] az, [48..79] cz, [80..111] ah, [112..143] ch
__global__ void precompute_k(const float* __restrict__ att,
                             const float* __restrict__ wc_z, const float* __restrict__ bc_z,
                             const float* __restrict__ wc_h, const float* __restrict__ bc_h,
                             const float* __restrict__ wl_z, const float* __restrict__ bl_z,
                             const float* __restrict__ wl_h, const float* __restrict__ bl_h,
                             float* __restrict__ tabs) {
    int j = threadIdx.x;
    if (j < FF) {
        float az = 0.f, cz = 0.f, ah = 0.f, ch = 0.f;
        for (int f = 0; f < FF; ++f) {
            float wz = wl_z[f * FF + j];
            float wh = wl_h[f * FF + j];
            az += wc_z[f] * wz;
            cz += bc_z[f] * wz;
            ah += wc_h[f] * wh;
            ch += bc_h[f] * wh;
        }
        tabs[16 + j]          = az;
        tabs[16 + FF + j]     = cz + bl_z[j];
        tabs[16 + 2 * FF + j] = ah;
        tabs[16 + 3 * FF + j] = ch + bl_h[j];
    } else if (j == FF) {
        float a[PP];
        float m = -1e30f;
        for (int p = 0; p < PP; ++p) { a[p] = att[p]; m = fmaxf(m, a[p]); }
        float s = 0.f;
        for (int p = 0; p < PP; ++p) { a[p] = __expf(a[p] - m); s += a[p]; }
        for (int p = 0; p < PP; ++p) tabs[p] = a[p] / s;
    }
}

// ---------------- K1: in-LDS counting sort via 4B perm word, linear write -----------
// perm[p] = (local<<13)|e. LDS 38.3KB -> 4 blocks/CU.
// T16[b*K1B + blk] = exclusive start of bucket b's run in chunk blk (rows 0..782)
__global__ __launch_bounds__(512) void bucketsort_k(const int* __restrict__ src,
                                                    const int* __restrict__ dst,
                                                    const float* __restrict__ ew,
                                                    uint2* __restrict__ recs,
                                                    unsigned short* __restrict__ T16) {
    __shared__ unsigned int perm[CHK]; // 32000 B
    __shared__ int hist[NBIN];
    __shared__ int offs[NBIN];
    int tid = threadIdx.x;
    int blk = blockIdx.x;
    int beg = blk * CHK;

    for (int b = tid; b < NBIN; b += 512) hist[b] = 0;
    __syncthreads();

    for (int e = tid; e < CHK; e += 512)
        atomicAdd(&hist[dst[beg + e] >> 7], 1);
    __syncthreads();

    // inclusive Hillis-Steele scan over hist[NBIN], 2 slots per thread
    int i2   = 512 + tid;
    int own0 = hist[tid];
    int own1 = (i2 < NBIN) ? hist[i2] : 0;
    for (int off = 1; off < NBIN; off <<= 1) {
        int a0 = (tid >= off) ? hist[tid - off] : 0;
        int a1 = (i2 < NBIN) ? hist[i2 - off] : 0;   // i2 >= 512 >= off always
        __syncthreads();
        hist[tid] += a0;
        if (i2 < NBIN) hist[i2] += a1;
        __syncthreads();
    }
    offs[tid] = hist[tid] - own0;
    if (i2 < NBIN) offs[i2] = hist[i2] - own1;
    __syncthreads();

    // run table (read offs before placement mutates it; barrier orders)
    for (int b = tid; b < BB + 1; b += 512)
        T16[(size_t)b * K1B + blk] = (unsigned short)offs[b];
    __syncthreads();

    // placement: LDS claim atomic + 4B perm store (dst re-read is L1/L2-hot)
    for (int e = tid; e < CHK; e += 512) {
        int d = dst[beg + e];
        int p = atomicAdd(&offs[d >> 7], 1);
        perm[p] = ((unsigned)(d & (VV - 1)) << 13) | (unsigned)e;
    }
    __syncthreads();

    // write-out: gather src/ew by perm (32KB windows, cache-hot), coalesced store
    uint2* o = recs + (size_t)blk * CHK;
    for (int k = tid; k < CHK; k += 512) {
        unsigned pe = perm[k];
        int e = (int)(pe & 0x1FFFu);
        uint2 r;
        r.x = ((pe >> 13) << 17) | (unsigned)src[beg + e];
        r.y = __float_as_uint(ew[beg + e]);
        o[k] = r;
    }
}

// ---------------- K2: per-(bucket,segment) degree partials (u64 fx, non-atomic out) -
__global__ __launch_bounds__(512) void deg2_k(const uint2* __restrict__ recs,
                                              const unsigned short* __restrict__ T16,
                                              unsigned long long* __restrict__ pdeg) {
    __shared__ unsigned long long wsum[VV];
    __shared__ unsigned short rstart[K1SEG];
    __shared__ int rpre[K1SEG + 1];
    int b   = blockIdx.x >> 1;
    int seg = blockIdx.x & 1;
    int tid = threadIdx.x;
    int k0  = seg * K1SEG;

    if (tid < VV) wsum[tid] = 0ull;
    if (tid < K1SEG) {
        int s = T16[(size_t)b * K1B + k0 + tid];
        int e = T16[(size_t)(b + 1) * K1B + k0 + tid];
        rstart[tid] = (unsigned short)s;
        rpre[tid]   = e - s;
    }
    __syncthreads();

    // inclusive scan over rpre[0..K1SEG-1]
    for (int off = 1; off < K1SEG; off <<= 1) {
        int a = (tid < K1SEG && tid >= off) ? rpre[tid - off] : 0;
        __syncthreads();
        if (tid < K1SEG) rpre[tid] += a;
        __syncthreads();
    }
    int inc = (tid < K1SEG) ? rpre[tid] : 0;
    __syncthreads();
    if (tid == 0) rpre[0] = 0;
    if (tid < K1SEG) rpre[tid + 1] = inc;
    __syncthreads();

    int n = rpre[K1SEG];
    for (int k = tid; k < n; k += 512) {
        int r = 0;
        #pragma unroll
        for (int s = 256; s; s >>= 1) {
            int c = r + s;
            if (c < K1SEG && rpre[c] <= k) r = c;
        }
        uint2 v = recs[(size_t)(k0 + r) * CHK + rstart[r] + (k - rpre[r])];
        unsigned long long w = (unsigned long long)(__uint_as_float(v.y) * 4294967296.0f);
        atomicAdd(&wsum[v.x >> 17], w);      // native integer LDS atomic
    }
    __syncthreads();

    int node = b * VV + tid;
    if (tid < VV && node < NN)
        pdeg[(size_t)seg * NN + node] = wsum[tid];
}

// ---------------- K2b: combine degree partials -> dinv, xds = dinv*x ---------------
__global__ __launch_bounds__(256) void xds_k(const unsigned long long* __restrict__ pdeg,
                                             const float* __restrict__ x,
                                             float* __restrict__ xds) {
    int i = blockIdx.x * 256 + threadIdx.x;
    if (i >= NN) return;
    float wf = (float)(pdeg[i] + pdeg[(size_t)NN + i]) * FPSI;
    float dv = rsqrtf(wf + 1.0f);
    const float4* xr = (const float4*)(x + (size_t)i * PP);
    float4* xo = (float4*)(xds + ((size_t)i << 4));
    #pragma unroll
    for (int q = 0; q < 3; ++q) {
        float4 v = xr[q];
        v.x *= dv; v.y *= dv; v.z *= dv; v.w *= dv;
        xo[q] = v;
    }
    xds[((size_t)i << 4) + 12] = dv;
}

// ---------------- K3: split sortagg -> partial agg (40.5KB LDS, 4 blocks/CU) --------
// block (b,seg): register-load seg's records, in-LDS node sort, register acc,
// write partial [128][12] f32 to pagg (non-atomic)
__global__ __launch_bounds__(512) void sortagg_k(const uint2* __restrict__ recs,
                                                 const unsigned short* __restrict__ T16,
                                                 const float* __restrict__ xds,
                                                 float* __restrict__ pagg) {
    __shared__ uint2 srec[CAP2];                   // 36608 B
    __shared__ int   h[VV], starts_s[VV], offs[VV];// 1536 B (h keeps inclusive ends)
    __shared__ unsigned short rstart[K1SEG];       // 800 B
    __shared__ int   rpre[K1SEG + 1];              // 1604 B   -> total 40548 B
    int b   = blockIdx.x >> 1;
    int seg = blockIdx.x & 1;
    int tid = threadIdx.x;
    int k0  = seg * K1SEG;

    if (tid < VV) h[tid] = 0;
    if (tid < K1SEG) {
        int s = T16[(size_t)b * K1B + k0 + tid];
        int e = T16[(size_t)(b + 1) * K1B + k0 + tid];
        rstart[tid] = (unsigned short)s;
        rpre[tid]   = e - s;
    }
    __syncthreads();

    for (int off = 1; off < K1SEG; off <<= 1) {
        int a = (tid < K1SEG && tid >= off) ? rpre[tid - off] : 0;
        __syncthreads();
        if (tid < K1SEG) rpre[tid] += a;
        __syncthreads();
    }
    int inc = (tid < K1SEG) ? rpre[tid] : 0;
    __syncthreads();
    if (tid == 0) rpre[0] = 0;
    if (tid < K1SEG) rpre[tid + 1] = inc;
    __syncthreads();

    int n = min(rpre[K1SEG], 512 * NR2);

    // dense load into REGISTERS (static unroll) + node histogram
    uint2 regs[NR2];
    #pragma unroll
    for (int w = 0; w < NR2; ++w) {
        int k = tid + w * 512;
        if (k < n) {
            int r = 0;
            #pragma unroll
            for (int s = 256; s; s >>= 1) {
                int c = r + s;
                if (c < K1SEG && rpre[c] <= k) r = c;
            }
            uint2 v = recs[(size_t)(k0 + r) * CHK + rstart[r] + (k - rpre[r])];
            regs[w] = v;
            atomicAdd(&h[v.x >> 17], 1);
        }
    }
    __syncthreads();

    // Hillis-Steele inclusive scan over h[VV]; h stays = inclusive end
    int own = (tid < VV) ? h[tid] : 0;
    #pragma unroll
    for (int off = 1; off < VV; off <<= 1) {
        int t = (tid < VV && tid >= off) ? h[tid - off] : 0;
        __syncthreads();
        if (tid < VV) h[tid] += t;
        __syncthreads();
    }
    if (tid < VV) {
        int pre = h[tid] - own;
        starts_s[tid] = pre;
        offs[tid]     = pre;
    }
    __syncthreads();

    // placement from registers
    #pragma unroll
    for (int w = 0; w < NR2; ++w) {
        int k = tid + w * 512;
        if (k < n) {
            uint2 v = regs[w];
            int p = atomicAdd(&offs[v.x >> 17], 1);
            if (p < CAP2) srec[p] = v;
        }
    }
    __syncthreads();

    // accumulate: 4 lanes per node, registers only
    int local = tid >> 2;
    int q     = tid & 3;
    int st = min(starts_s[local], CAP2);
    int en = min(h[local], CAP2);

    float acc[PP];
    #pragma unroll
    for (int p = 0; p < PP; ++p) acc[p] = 0.f;

    for (int m = st + q; m < en; m += 4) {
        uint2 v = srec[m];
        float c = __uint_as_float(v.y);
        const float4* xs = (const float4*)(xds + ((size_t)(v.x & 0x1FFFFu) << 4));
        float4 v0 = xs[0], v1 = xs[1], v2 = xs[2];
        acc[0] += c * v0.x;  acc[1] += c * v0.y;  acc[2]  += c * v0.z;  acc[3]  += c * v0.w;
        acc[4] += c * v1.x;  acc[5] += c * v1.y;  acc[6]  += c * v1.z;  acc[7]  += c * v1.w;
        acc[8] += c * v2.x;  acc[9] += c * v2.y;  acc[10] += c * v2.z;  acc[11] += c * v2.w;
    }

    // width-4 butterfly: all 4 lanes hold full sums
    #pragma unroll
    for (int p = 0; p < PP; ++p) {
        acc[p] += __shfl_xor(acc[p], 1, 4);
        acc[p] += __shfl_xor(acc[p], 2, 4);
    }

    // partial write: lane q writes floats 3q..3q+2 -> 48B contiguous per node
    float* ap = pagg + ((size_t)(seg * BB + b) * VV + local) * PP;
    ap[3 * q + 0] = acc[3 * q + 0];
    ap[3 * q + 1] = acc[3 * q + 1];
    ap[3 * q + 2] = acc[3 * q + 2];
}

// ---------------- K4: combine partials + fused GRU/attention/output -----------------
__global__ __launch_bounds__(512) void epi_k(const float* __restrict__ pagg,
                                             const float* __restrict__ xds,
                                             const float* __restrict__ tabs,
                                             const float* __restrict__ w_out,
                                             const float* __restrict__ b_out,
                                             float* __restrict__ out) {
    int b = blockIdx.x;
    int tid = threadIdx.x;
    int g = tid >> 5;
    int j = tid & 31;
    float azj = tabs[16 + j];
    float czj = tabs[16 + FF + j];
    float ahj = tabs[16 + 2 * FF + j];
    float chj = tabs[16 + 3 * FF + j];

    for (int nl = g; nl < VV; nl += 16) {
        int i = b * VV + nl;
        if (i >= NN) continue;            // uniform within the 32-lane group
        float dv = xds[((size_t)i << 4) + 12];
        const float* a0 = pagg + ((size_t)b * VV + nl) * PP;
        const float* a1 = pagg + ((size_t)(BB + b) * VV + nl) * PP;

        float accum = 0.f;
        #pragma unroll
        for (int p = 0; p < PP; ++p) {
            float ai = a0[p] + a1[p];
            float sp = dv * (ai + xds[((size_t)i << 4) + p]);  // edge sum + self
            float pr = tabs[p];
            float uz = sp * azj + czj;
            float uh = sp * ahj + chj;
            float one_minus_z = 1.0f / (1.0f + __expf(uz));   // sigma(-uz)
            float e2h = __expf(2.0f * uh);
            float th  = 1.0f - 2.0f / (e2h + 1.0f);           // tanh(uh)
            accum += pr * one_minus_z * th;
        }
        float hv = fmaxf(accum, 0.f) * w_out[j];
        #pragma unroll
        for (int off = 16; off > 0; off >>= 1)
            hv += __shfl_xor(hv, off, 32);
        if (j == 0) out[i] = hv + b_out[0];
    }
}

// ---------------- fallback path (round-2 proven kernels) ----------------
__global__ __launch_bounds__(256) void deg_k(const int* __restrict__ dst,
                                             const float* __restrict__ ew,
                                             float* __restrict__ deg) {
    int stride = gridDim.x * blockDim.x;
    for (int e = blockIdx.x * blockDim.x + threadIdx.x; e < EE; e += stride)
        atomicAdd(&deg[dst[e]], ew[e]);
}

__global__ __launch_bounds__(256) void dinv_self_k(const float* __restrict__ x,
                                                   float* __restrict__ deg,
                                                   float* __restrict__ agg) {
    int i = blockIdx.x * blockDim.x + threadIdx.x;
    if (i >= NN) return;
    float d  = deg[i] + 1.0f;
    float dv = rsqrtf(d);
    deg[i]   = dv;
    float dv2 = dv * dv;
    const float4* xr = (const float4*)(x + (size_t)i * PP);
    float4* ar = (float4*)(agg + (size_t)i * PP);
    #pragma unroll
    for (int q = 0; q < 3; ++q) {
        float4 v = xr[q];
        v.x *= dv2; v.y *= dv2; v.z *= dv2; v.w *= dv2;
        ar[q] = v;
    }
}

__global__ __launch_bounds__(256) void agg_k(const int* __restrict__ src,
                                             const int* __restrict__ dst,
                                             const float* __restrict__ ew,
                                             const float* __restrict__ x,
                                             const float* __restrict__ dinv,
                                             float* __restrict__ agg) {
    int stride = gridDim.x * blockDim.x;
    for (int e = blockIdx.x * blockDim.x + threadIdx.x; e < EE; e += stride) {
        int s = src[e];
        int d = dst[e];
        float nw = dinv[s] * ew[e] * dinv[d];
        const float4* xs = (const float4*)(x + (size_t)s * PP);
        float* ad = agg + (size_t)d * PP;
        float4 v0 = xs[0], v1 = xs[1], v2 = xs[2];
        atomicAdd(&ad[0],  nw * v0.x);
        atomicAdd(&ad[1],  nw * v0.y);
        atomicAdd(&ad[2],  nw * v0.z);
        atomicAdd(&ad[3],  nw * v0.w);
        atomicAdd(&ad[4],  nw * v1.x);
        atomicAdd(&ad[5],  nw * v1.y);
        atomicAdd(&ad[6],  nw * v1.z);
        atomicAdd(&ad[7],  nw * v1.w);
        atomicAdd(&ad[8],  nw * v2.x);
        atomicAdd(&ad[9],  nw * v2.y);
        atomicAdd(&ad[10], nw * v2.z);
        atomicAdd(&ad[11], nw * v2.w);
    }
}

__global__ __launch_bounds__(256) void node_k(const float* __restrict__ agg,
                                              const float* __restrict__ tabs,
                                              const float* __restrict__ w_out,
                                              const float* __restrict__ b_out,
                                              float* __restrict__ out) {
    int t = blockIdx.x * blockDim.x + threadIdx.x;
    int i = t >> 5;
    int j = t & 31;
    if (i >= NN) return;
    float azj = tabs[16 + j];
    float czj = tabs[16 + FF + j];
    float ahj = tabs[16 + 2 * FF + j];
    float chj = tabs[16 + 3 * FF + j];
    float acc = 0.f;
    #pragma unroll
    for (int p = 0; p < PP; ++p) {
        float s  = agg[i * PP + p];
        float pr = tabs[p];
        float uz = s * azj + czj;
        float uh = s * ahj + chj;
        float one_minus_z = 1.0f / (1.0f + __expf(uz));
        float e2h = __expf(2.0f * uh);
        float th  = 1.0f - 2.0f / (e2h + 1.0f);
        acc += pr * one_minus_z * th;
    }
    float h = fmaxf(acc, 0.f) * w_out[j];
    #pragma unroll
    for (int off = 16; off > 0; off >>= 1)
        h += __shfl_xor(h, off, 32);
    if (j == 0) out[i] = h + b_out[0];
}

extern "C" void kernel_launch(void* const* d_in, const int* in_sizes, int n_in,
                              void* d_out, int out_size, void* d_ws, size_t ws_size,
                              hipStream_t stream) {
    const float* x    = (const float*)d_in[0];
    const int*   ei   = (const int*)d_in[1];
    const float* ew   = (const float*)d_in[2];
    const float* att  = (const float*)d_in[3];
    const float* wc_z = (const float*)d_in[4];
    const float* bc_z = (const float*)d_in[5];
    const float* wc_h = (const float*)d_in[8];
    const float* bc_h = (const float*)d_in[9];
    const float* wl_z = (const float*)d_in[10];
    const float* bl_z = (const float*)d_in[11];
    const float* wl_h = (const float*)d_in[14];
    const float* bl_h = (const float*)d_in[15];
    const float* wout = (const float*)d_in[16];
    const float* bout = (const float*)d_in[17];
    float* out = (float*)d_out;

    const int* src = ei;
    const int* dst = ei + EE;

    size_t region  = (size_t)EE * sizeof(uint2);                        // 51.2 MB
    size_t tbl_sz  = (((size_t)(BB + 1) * K1B * 2) + 63) & ~63ull;      // ~1.25 MB
    size_t xds_sz  = (size_t)NN * XST * sizeof(float);                  // 6.4 MB
    size_t pdeg_sz = (size_t)2 * NN * sizeof(unsigned long long);       // 1.6 MB
    size_t pagg_sz = (size_t)2 * BB * VV * PP * sizeof(float);          // 9.6 MB
    size_t need    = region + tbl_sz + xds_sz + pdeg_sz + pagg_sz + 4096;

    if (ws_size >= need) {
        char* base = (char*)d_ws;
        uint2*              recs = (uint2*)base;                 base += region;
        unsigned short*     T16  = (unsigned short*)base;        base += tbl_sz;
        float*              xds  = (float*)base;                 base += xds_sz;
        unsigned long long* pdeg = (unsigned long long*)base;    base += pdeg_sz;
        float*              pagg = (float*)base;                 base += pagg_sz;
        float*              tabs = (float*)base;

        precompute_k<<<1, 64, 0, stream>>>(att, wc_z, bc_z, wc_h, bc_h, wl_z, bl_z, wl_h, bl_h, tabs);
        bucketsort_k<<<K1B, 512, 0, stream>>>(src, dst, ew, recs, T16);
        deg2_k<<<BB * 2, 512, 0, stream>>>(recs, T16, pdeg);
        xds_k<<<(NN + 255) / 256, 256, 0, stream>>>(pdeg, x, xds);
        sortagg_k<<<BB * 2, 512, 0, stream>>>(recs, T16, xds, pagg);
        epi_k<<<BB, 512, 0, stream>>>(pagg, xds, tabs, wout, bout, out);
    } else {
        float* deg  = (float*)d_ws;
        float* agg  = deg + NN;
        float* tabs = agg + (size_t)NN * PP;

        hipMemsetAsync(deg, 0, NN * sizeof(float), stream);
        precompute_k<<<1, 64, 0, stream>>>(att, wc_z, bc_z, wc_h, bc_h, wl_z, bl_z, wl_h, bl_h, tabs);
        deg_k<<<4096, 256, 0, stream>>>(dst, ew, deg);
        dinv_self_k<<<(NN + 255) / 256, 256, 0, stream>>>(x, deg, agg);
        agg_k<<<8192, 256, 0, stream>>>(src, dst, ew, x, deg, agg);
        node_k<<<NN * 32 / 256, 256, 0, stream>>>(agg, tabs, wout, bout, out);
    }
}